// Round 2
// baseline (347.886 us; speedup 1.0000x reference)
//
#include <hip/hip_runtime.h>
#include <stdint.h>

// Problem constants: B=8, N=2048, F_in=F_out=512
#define NB 8
#define NN 2048
#define NF 512
#define TOTN (NB * NN)   // 16384 nodes total

typedef unsigned short u16;
typedef short bf16x8 __attribute__((ext_vector_type(8)));
typedef float f32x4 __attribute__((ext_vector_type(4)));

__device__ __forceinline__ u16 f2bf(float x) {
  unsigned u = __float_as_uint(x);
  unsigned r = 0x7FFFu + ((u >> 16) & 1u);
  return (u16)((u + r) >> 16);
}
__device__ __forceinline__ float bf2f(u16 u) {
  return __uint_as_float(((unsigned)u) << 16);
}

__device__ __forceinline__ void gl2lds16(const void* g, void* l) {
  // async global->LDS, 16B per lane; LDS dst = wave-uniform base + lane*16
  __builtin_amdgcn_global_load_lds((const __attribute__((address_space(1))) void*)g,
                                   (__attribute__((address_space(3))) void*)l,
                                   16, 0, 0);
}

// ---------------------------------------------------------------------------
// K1: convert text (8.4M fp32) -> bf16, and W -> W^T bf16 (so GEMM1's A operand
// is K-contiguous). Blocks [0,8192) do text (float4 each), [8192,9216) do W^T.
// ---------------------------------------------------------------------------
__global__ __launch_bounds__(256) void conv_kernel(
    const float* __restrict__ text, const float* __restrict__ W,
    u16* __restrict__ text_bf, u16* __restrict__ Wt) {
  int blk = blockIdx.x;
  if (blk < 8192) {
    int idx = blk * 256 + threadIdx.x;       // float4 index, 2,097,152 total
    float4 v = ((const float4*)text)[idx];
    ushort4 o;
    o.x = f2bf(v.x); o.y = f2bf(v.y); o.z = f2bf(v.z); o.w = f2bf(v.w);
    ((ushort4*)text_bf)[idx] = o;
  } else {
    int t = (blk - 8192) * 256 + threadIdx.x;  // 0..262143
    int o = t >> 9, f = t & 511;
    Wt[o * NF + f] = f2bf(W[f * NF + o]);      // Wt[o][f] = W[f][o]
  }
}

// ---------------------------------------------------------------------------
// K2: GEMM1  hiddenT[o][node] = sum_f Wt[o][f]*text_bf[node][f] + bias[o]
// 128x128 tile, BK=32, 4 waves x (64x64), m97-style global_load_lds staging.
// ---------------------------------------------------------------------------
__global__ __launch_bounds__(256) void gemm1_kernel(
    const u16* __restrict__ A,   // Wt [512][512]
    const u16* __restrict__ Bt,  // text_bf [16384][512]
    const float* __restrict__ bias, u16* __restrict__ hT) {
  __shared__ u16 Alds[128 * 32];
  __shared__ u16 Blds[128 * 32];

  const int bn = blockIdx.x, bm = blockIdx.y;
  const int t = threadIdx.x, wave = t >> 6, lane = t & 63;
  const int wm = (wave >> 1) * 64, wn = (wave & 1) * 64;

  f32x4 acc[4][4];
#pragma unroll
  for (int i = 0; i < 4; ++i)
#pragma unroll
    for (int j = 0; j < 4; ++j) acc[i][j] = (f32x4){0.f, 0.f, 0.f, 0.f};

  const int rowA0 = bm * 128, rowB0 = bn * 128;
  const int srow = (lane >> 2);
  const int scol = (lane & 3) * 8;

  for (int kt = 0; kt < NF; kt += 32) {
#pragma unroll
    for (int q = 0; q < 2; ++q) {
      int r = wave * 32 + q * 16;
      gl2lds16(A + (size_t)(rowA0 + r + srow) * NF + (kt + scol), &Alds[r * 32]);
    }
#pragma unroll
    for (int q = 0; q < 2; ++q) {
      int r = wave * 32 + q * 16;
      gl2lds16(Bt + (size_t)(rowB0 + r + srow) * NF + (kt + scol), &Blds[r * 32]);
    }
    __syncthreads();

    const int fr = lane & 15;
    const int k0 = (lane >> 4) * 8;
    bf16x8 af[4], bfr[4];
#pragma unroll
    for (int i = 0; i < 4; ++i)
      af[i] = *(const bf16x8*)&Alds[(wm + i * 16 + fr) * 32 + k0];
#pragma unroll
    for (int j = 0; j < 4; ++j)
      bfr[j] = *(const bf16x8*)&Blds[(wn + j * 16 + fr) * 32 + k0];
#pragma unroll
    for (int i = 0; i < 4; ++i)
#pragma unroll
      for (int j = 0; j < 4; ++j)
        acc[i][j] = __builtin_amdgcn_mfma_f32_16x16x32_bf16(af[i], bfr[j],
                                                            acc[i][j], 0, 0, 0);
    __syncthreads();
  }

  const int quad = lane >> 4, ln16 = lane & 15;
#pragma unroll
  for (int i = 0; i < 4; ++i) {
    int m0 = bm * 128 + wm + i * 16 + quad * 4;
#pragma unroll
    for (int r = 0; r < 4; ++r) {
      int m = m0 + r;
      float bv = bias[m];
#pragma unroll
      for (int j = 0; j < 4; ++j) {
        int n = bn * 128 + wn + j * 16 + ln16;
        hT[(size_t)m * TOTN + n] = f2bf(acc[i][j][r] + bv);
      }
    }
  }
}

// ---------------------------------------------------------------------------
// K3: per-node scores s[n]=sum_o hT[o][n]*a_src[o], d likewise.
// 256 blocks; each block: 64 nodes x 4 o-phases (one wave per phase), LDS reduce.
// ---------------------------------------------------------------------------
__global__ __launch_bounds__(256) void sd_kernel(
    const u16* __restrict__ hT, const float* __restrict__ a_src,
    const float* __restrict__ a_dst, float* __restrict__ s,
    float* __restrict__ d) {
  __shared__ float red[2][256];
  int nb = blockIdx.x * 64;
  int nl = threadIdx.x & 63;
  int oo = threadIdx.x >> 6;     // 0..3 (== wave id)
  int n = nb + nl;
  float as = 0.f, ad = 0.f;
#pragma unroll 4
  for (int o = oo; o < NF; o += 4) {
    float h = bf2f(hT[(size_t)o * TOTN + n]);
    as = fmaf(h, a_src[o], as);
    ad = fmaf(h, a_dst[o], ad);
  }
  red[0][threadIdx.x] = as;
  red[1][threadIdx.x] = ad;
  __syncthreads();
  if (threadIdx.x < 64) {
    int tt = threadIdx.x;
    s[nb + tt] = red[0][tt] + red[0][tt + 64] + red[0][tt + 128] + red[0][tt + 192];
    d[nb + tt] = red[1][tt] + red[1][tt + 64] + red[1][tt + 128] + red[1][tt + 192];
  }
}

// ---------------------------------------------------------------------------
// K4 (fused): out[z,i,o] = (1/l_i) * sum_j exp(lrelu(s_i+d_j))·[!adj]·hT[o][z*N+j]
// Flash-style: P tile generated in-register -> LDS (A-frag layout), no P buffer,
// adj read exactly once. Block = 512 thr (8 waves), M-tile=64 i, N=512 o (full),
// K-loop over j in BK=32. Wave w -> o range [w*64, w*64+64). Grid (32, 8).
// ---------------------------------------------------------------------------
__global__ __launch_bounds__(512, 2) void fused_attn_kernel(
    const int* __restrict__ adj, const float* __restrict__ s,
    const float* __restrict__ d, const u16* __restrict__ hT,
    float* __restrict__ out) {
  __shared__ u16 Plds[64 * 32];       // P tile [i][k], A-operand layout
  __shared__ u16 Blds[512 * 32];      // hT tile [o][k]
  __shared__ float lpart[64 * 8];
  __shared__ float linv_lds[64];

  const int z = blockIdx.y;
  const int i0 = blockIdx.x * 64;
  const int t = threadIdx.x, wave = t >> 6, lane = t & 63;

  // P-generation mapping: 8 threads per row, 4 j's each per 32-chunk
  const int pr = t >> 3;          // row 0..63
  const int pj = (t & 7) * 4;     // j offset 0,4,..,28
  const float si = s[z * NN + i0 + pr];
  const int* arow = adj + (size_t)(z * NN + i0 + pr) * NN;
  const float* db = d + z * NN;

  // B-staging mapping
  const int so = wave * 16 + (lane >> 2);   // o within 128-group
  const int sc = (lane & 3) * 8;            // k col (8 bf16 = 16B)

  f32x4 acc[4][4];
#pragma unroll
  for (int i = 0; i < 4; ++i)
#pragma unroll
    for (int j = 0; j < 4; ++j) acc[i][j] = (f32x4){0.f, 0.f, 0.f, 0.f};

  float lsum = 0.f;
  const int ln16 = lane & 15, quad = lane >> 4;

  for (int kt = 0; kt < NN; kt += 32) {
    // --- generate P tile [64][32] in A-frag-friendly row-major layout ---
    int4 a4 = *(const int4*)&arow[kt + pj];
    float4 d4 = *(const float4*)&db[kt + pj];
    float x0 = si + d4.x, x1 = si + d4.y, x2 = si + d4.z, x3 = si + d4.w;
    x0 = fmaxf(x0, 0.2f * x0); x1 = fmaxf(x1, 0.2f * x1);
    x2 = fmaxf(x2, 0.2f * x2); x3 = fmaxf(x3, 0.2f * x3);
    float p0 = a4.x ? 0.f : __expf(x0);
    float p1 = a4.y ? 0.f : __expf(x1);
    float p2 = a4.z ? 0.f : __expf(x2);
    float p3 = a4.w ? 0.f : __expf(x3);
    lsum += (p0 + p1) + (p2 + p3);
    ushort4 pk;
    pk.x = f2bf(p0); pk.y = f2bf(p1); pk.z = f2bf(p2); pk.w = f2bf(p3);
    *(ushort4*)&Plds[pr * 32 + pj] = pk;

    // --- stage B tile hT[512 o][32 k] (32 KB) via async global->LDS ---
#pragma unroll
    for (int q = 0; q < 4; ++q) {
      int ob = q * 128 + so;  // o row for this lane
      gl2lds16(hT + (size_t)ob * TOTN + z * NN + kt + sc,
               &Blds[(q * 128 + wave * 16) * 32]);
    }
    __syncthreads();

    // --- fragments + MFMA: wave-tile 64(i) x 64(o) ---
    bf16x8 af[4], bfr[4];
#pragma unroll
    for (int i = 0; i < 4; ++i)
      af[i] = *(const bf16x8*)&Plds[(i * 16 + ln16) * 32 + quad * 8];
#pragma unroll
    for (int j = 0; j < 4; ++j)
      bfr[j] = *(const bf16x8*)&Blds[(wave * 64 + j * 16 + ln16) * 32 + quad * 8];
#pragma unroll
    for (int i = 0; i < 4; ++i)
#pragma unroll
      for (int j = 0; j < 4; ++j)
        acc[i][j] = __builtin_amdgcn_mfma_f32_16x16x32_bf16(af[i], bfr[j],
                                                            acc[i][j], 0, 0, 0);
    __syncthreads();
  }

  // --- row sums -> 1/l ---
  lpart[pr * 8 + (t & 7)] = lsum;
  __syncthreads();
  if (t < 64) {
    const float* lp = &lpart[t * 8];
    float tot = ((lp[0] + lp[1]) + (lp[2] + lp[3])) +
                ((lp[4] + lp[5]) + (lp[6] + lp[7]));
    linv_lds[t] = 1.0f / tot;
  }
  __syncthreads();

  // --- epilogue: C/D layout col=lane&15, row=quad*4+reg ---
#pragma unroll
  for (int i = 0; i < 4; ++i) {
    int m0 = i * 16 + quad * 4;
#pragma unroll
    for (int r = 0; r < 4; ++r) {
      int m = m0 + r;
      float sc2 = linv_lds[m];
      size_t base = (size_t)(z * NN + i0 + m) * NF;
#pragma unroll
      for (int j = 0; j < 4; ++j) {
        int o = wave * 64 + j * 16 + ln16;
        out[base + o] = acc[i][j][r] * sc2;
      }
    }
  }
}

// ---------------------------------------------------------------------------
// launch
// ---------------------------------------------------------------------------
extern "C" void kernel_launch(void* const* d_in, const int* in_sizes, int n_in,
                              void* d_out, int out_size, void* d_ws,
                              size_t ws_size, hipStream_t stream) {
  const float* text  = (const float*)d_in[0];   // [8,2048,512] fp32
  const int*   adj   = (const int*)d_in[1];     // [8,2048,2048] int32
  const float* W     = (const float*)d_in[2];   // [512,512] fp32
  const float* bias  = (const float*)d_in[3];   // [512] fp32 (zeros)
  const float* a_src = (const float*)d_in[4];   // [512] fp32
  const float* a_dst = (const float*)d_in[5];   // [512] fp32
  float* out = (float*)d_out;                   // [8,2048,512] fp32

  // ws layout (bytes), total ~34.3 MB
  char* ws = (char*)d_ws;
  u16*   text_bf = (u16*)(ws + 0);              // 16,777,216
  u16*   Wt      = (u16*)(ws + 16777216);       //    524,288
  u16*   hT      = (u16*)(ws + 17301504);       // 16,777,216  [512][16384]
  float* s       = (float*)(ws + 34078720);     //     65,536
  float* d       = (float*)(ws + 34144256);     //     65,536

  conv_kernel<<<9216, 256, 0, stream>>>(text, W, text_bf, Wt);

  // hiddenT[o][node]: M=512 (grid.y=4), N'=16384 (grid.x=128), K=512
  gemm1_kernel<<<dim3(128, 4, 1), 256, 0, stream>>>(Wt, text_bf, bias, hT);

  sd_kernel<<<TOTN / 64, 256, 0, stream>>>(hT, a_src, a_dst, s, d);

  // fused mask+softmax+PV: grid (i-tiles of 64, batch)
  fused_attn_kernel<<<dim3(NN / 64, NB, 1), 512, 0, stream>>>(adj, s, d, hT, out);
}